// Round 1
// 630.557 us; speedup vs baseline: 3.7284x; 3.7284x over previous
//
#include <hip/hip_runtime.h>
#include <math.h>

#define BB 32     // batch
#define TT 64     // time steps
#define VV 32000  // vocab
#define HH 32     // hidden
#define EE 200    // embedding dim
#define VC 32     // vocab chunks for the stats pass
#define CHUNK (VV / VC)  // 1000
#define WVT 125   // k_write v-tiles: VV / 256

// ---------------- Kernel 1: i2h = emb_table[y] @ Wi.T + bi + bh ----------------
__global__ void k_i2h(const int* __restrict__ y, const float* __restrict__ emb,
                      const float* __restrict__ Wi, const float* __restrict__ bi,
                      const float* __restrict__ bh, float* __restrict__ i2h) {
    int bt = blockIdx.x;              // 0..2047  (= b*TT + t)
    int tok = y[bt];
    __shared__ float se[EE];
    for (int e = threadIdx.x; e < EE; e += blockDim.x) se[e] = emb[(size_t)tok * EE + e];
    __syncthreads();
    int h = threadIdx.x >> 3;         // 0..31
    int j = threadIdx.x & 7;          // 8 lanes per h
    float acc = 0.f;
    for (int e = j; e < EE; e += 8) acc += se[e] * Wi[h * EE + e];
    acc += __shfl_down(acc, 4, 8);
    acc += __shfl_down(acc, 2, 8);
    acc += __shfl_down(acc, 1, 8);
    if (j == 0) i2h[bt * HH + h] = acc + bi[h] + bh[h];
}

// ---------------- Kernel 2: recurrence h_t = tanh(i2h_t + h_{t-1} @ Wh.T) ------
__global__ void k_rnn(const float* __restrict__ enc, const float* __restrict__ Wh,
                      const float* __restrict__ i2h, float* __restrict__ hall) {
    int b = blockIdx.x;               // 0..31
    int tid = threadIdx.x;            // 64 threads = 1 wave
    __shared__ float hs[HH];
    __shared__ float sWh[HH][HH + 1]; // +1 pad: breaks 32-way bank conflict on row reads
    __shared__ float si[TT * HH];     // all i2h for this b (8 KB)
    for (int i = tid; i < HH * HH; i += 64) sWh[i >> 5][i & 31] = Wh[i];
    for (int i = tid; i < TT * HH; i += 64) si[i] = i2h[b * TT * HH + i];
    if (tid < HH) hs[tid] = enc[b * HH + tid];
    __syncthreads();
    for (int t = 0; t < TT; ++t) {
        float hv = 0.f;
        if (tid < HH) {
            float a0 = si[t * HH + tid], a1 = 0.f, a2 = 0.f, a3 = 0.f;
#pragma unroll
            for (int j = 0; j < HH; j += 4) {
                a0 += sWh[tid][j]     * hs[j];
                a1 += sWh[tid][j + 1] * hs[j + 1];
                a2 += sWh[tid][j + 2] * hs[j + 2];
                a3 += sWh[tid][j + 3] * hs[j + 3];
            }
            hv = tanhf((a0 + a1) + (a2 + a3));
        }
        __syncthreads();
        if (tid < HH) {
            hs[tid] = hv;
            hall[(b * TT + t) * HH + tid] = hv;
        }
        __syncthreads();
    }
}

// ---------------- Kernel 3: per-chunk stats (max, argmax, sum of exp) ----------
// grid = (VC, TT), block = 256 = 4 waves. Wave w owns b in [8w, 8w+8): per-thread
// stats arrays are 8-deep (24 VGPRs) instead of 32-deep (96 VGPRs) -> no scratch
// spill (the old version's 357 MB WRITE_SIZE), and 4x the waves for latency hiding.
// The 4 waves redundantly stream the same 128 KB Wo chunk: L1/L2-resident, cheap.
// |logit| < 6 so exp() without max-subtraction is safe; partial sums add directly.
__global__ __launch_bounds__(256) void k_stats(
        const float* __restrict__ Wo, const float* __restrict__ bo,
        const float* __restrict__ hall,
        float* __restrict__ pmax, float* __restrict__ pamx, float* __restrict__ psum) {
    int t = blockIdx.y;
    int c = blockIdx.x;
    int v0 = c * CHUNK;
    int wv = threadIdx.x >> 6;        // wave id 0..3 -> b-group
    int l  = threadIdx.x & 63;        // lane in wave
    int b0 = wv * 8;
    __shared__ __align__(16) float shs[BB][HH];
    for (int i = threadIdx.x; i < BB * HH; i += 256) {
        int b = i >> 5, k = i & 31;
        shs[b][k] = hall[(b * TT + t) * HH + k];
    }
    __syncthreads();

    float mx[8], am[8], sm[8];
#pragma unroll
    for (int j = 0; j < 8; ++j) { mx[j] = -1e30f; am[j] = 0.f; sm[j] = 0.f; }

    for (int v = v0 + l; v < v0 + CHUNK; v += 64) {
        const float4* wrow = (const float4*)(Wo + (size_t)v * HH);
        float4 w[8];
#pragma unroll
        for (int q = 0; q < 8; ++q) w[q] = wrow[q];
        float bov = bo[v];
        float vf = (float)v;
#pragma unroll
        for (int j = 0; j < 8; ++j) {
            const float4* hb = (const float4*)&shs[b0 + j][0];  // wave-uniform: LDS broadcast
            float acc = bov;
#pragma unroll
            for (int q = 0; q < 8; ++q) {
                float4 hq = hb[q];
                acc += hq.x * w[q].x + hq.y * w[q].y + hq.z * w[q].z + hq.w * w[q].w;
            }
            sm[j] += __expf(acc);
            if (acc > mx[j]) { mx[j] = acc; am[j] = vf; }
        }
    }

    // per-wave butterfly reduce (64 lanes); first-occurrence tie -> smaller index
#pragma unroll
    for (int j = 0; j < 8; ++j) {
#pragma unroll
        for (int off = 32; off > 0; off >>= 1) {
            float m2 = __shfl_down(mx[j], off);
            float a2 = __shfl_down(am[j], off);
            float s2 = __shfl_down(sm[j], off);
            sm[j] += s2;
            if (m2 > mx[j] || (m2 == mx[j] && a2 < am[j])) { mx[j] = m2; am[j] = a2; }
        }
    }
    if (l == 0) {   // b-groups are disjoint: no cross-wave reduction needed
        int base = (t * VC + c) * BB + b0;
#pragma unroll
        for (int j = 0; j < 8; ++j) {
            pmax[base + j] = mx[j];
            pamx[base + j] = am[j];
            psum[base + j] = sm[j];
        }
    }
}

// ---------------- Kernel 4: combine partials -> lse, preds ---------------------
__global__ void k_combine(const float* __restrict__ pmax, const float* __restrict__ pamx,
                          const float* __restrict__ psum,
                          float* __restrict__ lse, float* __restrict__ preds) {
    int r = blockIdx.x * blockDim.x + threadIdx.x;   // r = b*TT + t
    if (r >= BB * TT) return;
    int b = r >> 6, t = r & 63;
    float m = -1e30f, a = 0.f, s = 0.f;
    for (int c = 0; c < VC; ++c) {
        int idx = (t * VC + c) * BB + b;
        float m2 = pmax[idx], a2 = pamx[idx];
        s += psum[idx];
        if (m2 > m || (m2 == m && a2 < a)) { m = m2; a = a2; }
    }
    lse[r] = logf(s);
    preds[r] = a;    // preds[b][t], index value as float (exact up to 2^24)
}

// ---------------- Kernel 5: recompute logits, write logp -----------------------
// One thread per vocab entry; grid (125, 64), block 256 = 4 waves. 8000 blocks
// (vs 2048 1-wave blocks before) -> full occupancy; per b, a wave stores 256 B x4
// contiguous. Roofline: the 262 MB output write.
__global__ __launch_bounds__(256) void k_write(
        const float* __restrict__ Wo, const float* __restrict__ bo,
        const float* __restrict__ hall, const float* __restrict__ lse,
        float* __restrict__ out) {
    int t = blockIdx.y;
    int v = blockIdx.x * 256 + (int)threadIdx.x;     // 0..31999 (exact: 125*256)
    __shared__ __align__(16) float shs[BB][HH];
    __shared__ float sl[BB];
    for (int i = threadIdx.x; i < BB * HH; i += 256) {
        int b = i >> 5, k = i & 31;
        shs[b][k] = hall[(b * TT + t) * HH + k];
    }
    if (threadIdx.x < BB) sl[threadIdx.x] = lse[threadIdx.x * TT + t];
    __syncthreads();

    const float4* wrow = (const float4*)(Wo + (size_t)v * HH);
    float4 w[8];
#pragma unroll
    for (int q = 0; q < 8; ++q) w[q] = wrow[q];
    float bov = bo[v];
    size_t obase = (size_t)t * VV + v;
#pragma unroll
    for (int b = 0; b < BB; ++b) {
        const float4* hb = (const float4*)&shs[b][0];   // wave-uniform: LDS broadcast
        float acc = bov - sl[b];
#pragma unroll
        for (int q = 0; q < 8; ++q) {
            float4 hq = hb[q];
            acc += hq.x * w[q].x + hq.y * w[q].y + hq.z * w[q].z + hq.w * w[q].w;
        }
        out[(size_t)b * TT * VV + obase] = acc;
    }
}

// ---------------- Launch -------------------------------------------------------
extern "C" void kernel_launch(void* const* d_in, const int* in_sizes, int n_in,
                              void* d_out, int out_size, void* d_ws, size_t ws_size,
                              hipStream_t stream) {
    const int*   y   = (const int*)  d_in[0];
    const float* enc = (const float*)d_in[1];
    const float* emb = (const float*)d_in[2];
    const float* Wi  = (const float*)d_in[3];
    const float* bi  = (const float*)d_in[4];
    const float* Wh  = (const float*)d_in[5];
    const float* bh  = (const float*)d_in[6];
    const float* Wo  = (const float*)d_in[7];
    const float* bo  = (const float*)d_in[8];
    float* out = (float*)d_out;
    float* ws  = (float*)d_ws;

    // workspace layout (floats)
    float* i2h  = ws;                 // 65536
    float* hall = ws + 65536;         // 65536
    float* pmax = ws + 131072;        // TT*VC*BB = 65536
    float* pamx = ws + 196608;        // 65536
    float* psum = ws + 262144;        // 65536
    float* lse  = ws + 327680;        // 2048

    k_i2h<<<BB * TT, 256, 0, stream>>>(y, emb, Wi, bi, bh, i2h);
    k_rnn<<<BB, 64, 0, stream>>>(enc, Wh, i2h, hall);
    dim3 gs(VC, TT);
    k_stats<<<gs, 256, 0, stream>>>(Wo, bo, hall, pmax, pamx, psum);
    k_combine<<<(BB * TT + 255) / 256, 256, 0, stream>>>(pmax, pamx, psum, lse,
                                                         out + (size_t)BB * TT * VV);
    dim3 gw(WVT, TT);
    k_write<<<gw, 256, 0, stream>>>(Wo, bo, hall, lse, out);
}